// Round 17
// baseline (35.562 us; speedup 1.0000x reference)
//
#include <hip/hip_runtime.h>
#include <hip/hip_bf16.h>
#include <math.h>

#define DD_ 256
#define HH_ 512
#define OO_ 64

typedef __attribute__((ext_vector_type(8))) short bf16x8s;
typedef __attribute__((ext_vector_type(4))) float f32x4;
typedef __attribute__((ext_vector_type(4))) unsigned int u32x4;

__device__ __forceinline__ unsigned short f2bf(float f) {
    unsigned u = __float_as_uint(f);
    u += 0x7FFF + ((u >> 16) & 1);   // round-to-nearest-even
    return (unsigned short)(u >> 16);
}
__device__ __forceinline__ float bf2f(unsigned short h) {
    return __uint_as_float(((unsigned)h) << 16);
}
// pack two floats -> one u32 of 2 bf16 (RNE); compiler emits v_cvt_pk_bf16_f32
__device__ __forceinline__ unsigned pk2(float a, float b) {
    __hip_bfloat162 h = __float22bfloat162_rn(make_float2(a, b));
    return *reinterpret_cast<unsigned*>(&h);
}
// 8 floats -> bf16 hi (packed u32x4), via cvt_pk
__device__ __forceinline__ u32x4 pk8hi(const float4& v0, const float4& v1) {
    u32x4 hi;
    hi[0] = pk2(v0.x, v0.y);
    hi[1] = pk2(v0.z, v0.w);
    hi[2] = pk2(v1.x, v1.y);
    hi[3] = pk2(v1.z, v1.w);
    return hi;
}
// 8 floats -> hi/lo bf16 split (4 u32 each), via cvt_pk
__device__ __forceinline__ void cvt8hl(const float4& v0, const float4& v1,
                                       u32x4& hi, u32x4& lo) {
    float f[8] = {v0.x, v0.y, v0.z, v0.w, v1.x, v1.y, v1.z, v1.w};
    #pragma unroll
    for (int e = 0; e < 4; ++e) {
        float a = f[2 * e], b = f[2 * e + 1];
        unsigned h = pk2(a, b);
        float ra = a - __uint_as_float(h << 16);
        float rb = b - __uint_as_float(h & 0xFFFF0000u);
        hi[e] = h;
        lo[e] = pk2(ra, rb);
    }
}
// 16-slot XOR swizzle within a 256B LDS row (slot = 16B); XOR of low 3 bits
// keeps staging writes and frag reads on the same involution, >=2-way banks.
__device__ __forceinline__ int swz16(int r, int s) {
    return s ^ (r & 7);
}
// tanh via v_exp_f32; |err| ~1e-6
__device__ __forceinline__ float fast_tanh(float z) {
    float e = __expf(2.f * z);
    return 1.f - __fdividef(2.f, e + 1.f);
}

// ============ L1 mega-kernel: grid 640 ============
// bb < 512: fused gemm1 (BK=128, 2 k-steps, 4 barriers; 2-term split-bf16)
//           + tanh + build Mt + b1/hd partials.
// bb >= 512: build Xt[256][6144] bf16 (independent work, same launch).
__global__ __launch_bounds__(256) void k_mega(
    const float* __restrict__ x, const float* __restrict__ W1,
    const float* __restrict__ b1, const float* __restrict__ W2,
    const int* __restrict__ ap, const int* __restrict__ pI,
    const int* __restrict__ an, const int* __restrict__ nI,
    short* __restrict__ Mt, short* __restrict__ Xt,
    float* __restrict__ pb1, float* __restrict__ phd) {
    const int t = threadIdx.x;
    const int bb = blockIdx.x;
    if (bb < 512) {
        __shared__ short Ah[64 * 128], Bh[64 * 128], Bl[64 * 128];   // 48 KB
        __shared__ float ht[64][67];   // pad 67: pair-read conflict-free
        __shared__ int sidx[64];
        const int n0 = (bb & 7) * 64;
        const int ry = bb >> 3;
        const int s = ry >> 5;
        const int p0 = (ry & 31) * 32;
        const int* IA = s ? an : ap;
        const int* IB = s ? nI : pI;
        if (t < 32) sidx[t] = IA[p0 + t];
        else if (t < 64) sidx[t] = IB[p0 + t - 32];
        __syncthreads();
        const int row = t >> 2, q = t & 3;          // staging: row 0..63, 32-float slice
        const int l = t & 63, w = t >> 6;
        const int wm = w >> 1, wn = w & 1;          // wave 2x2 over 64x64 tile
        const int lm = l & 15, g = l >> 4;          // frag: m/n = lm, k-slot = g
        const float* srcA = x + (size_t)sidx[row] * DD_ + q * 32;
        const float* srcB = W1 + (size_t)(n0 + row) * DD_ + q * 32;
        f32x4 acc[2][2] = {};
        for (int ks = 0; ks < 2; ++ks) {            // BK=128: 2 k-steps
            const int k0 = ks * 128;
            {   // stage A: gathered x rows, fp32 -> bf16 hi only (32 el/thread)
                #pragma unroll
                for (int jj = 0; jj < 4; ++jj) {
                    float4 a0 = *(const float4*)(srcA + k0 + jj * 8);
                    float4 a1 = *(const float4*)(srcA + k0 + jj * 8 + 4);
                    *(u32x4*)(&Ah[row * 128 + swz16(row, q * 4 + jj) * 8]) = pk8hi(a0, a1);
                }
            }
            {   // stage B: W1 rows, hi/lo split (32 el/thread)
                #pragma unroll
                for (int jj = 0; jj < 4; ++jj) {
                    float4 b0 = *(const float4*)(srcB + k0 + jj * 8);
                    float4 b1q = *(const float4*)(srcB + k0 + jj * 8 + 4);
                    u32x4 hi, lo;
                    cvt8hl(b0, b1q, hi, lo);
                    const int sl = swz16(row, q * 4 + jj) * 8;
                    *(u32x4*)(&Bh[row * 128 + sl]) = hi;
                    *(u32x4*)(&Bl[row * 128 + sl]) = lo;
                }
            }
            __syncthreads();
            #pragma unroll
            for (int kk = 0; kk < 4; ++kk) {        // four K=32 MFMA sub-steps
                bf16x8s ah[2], bh[2], bl[2];
                #pragma unroll
                for (int mi = 0; mi < 2; ++mi) {
                    int r = wm * 32 + mi * 16 + lm;
                    ah[mi] = *(const bf16x8s*)(&Ah[r * 128 + swz16(r, kk * 4 + g) * 8]);
                }
                #pragma unroll
                for (int nj = 0; nj < 2; ++nj) {
                    int r = wn * 32 + nj * 16 + lm;
                    int off = r * 128 + swz16(r, kk * 4 + g) * 8;
                    bh[nj] = *(const bf16x8s*)(&Bh[off]);
                    bl[nj] = *(const bf16x8s*)(&Bl[off]);
                }
                #pragma unroll
                for (int mi = 0; mi < 2; ++mi)
                    #pragma unroll
                    for (int nj = 0; nj < 2; ++nj) {
                        acc[mi][nj] = __builtin_amdgcn_mfma_f32_16x16x32_bf16(ah[mi], bh[nj], acc[mi][nj], 0, 0, 0);
                        acc[mi][nj] = __builtin_amdgcn_mfma_f32_16x16x32_bf16(ah[mi], bl[nj], acc[mi][nj], 0, 0, 0);
                    }
            }
            __syncthreads();
        }
        // h-tile -> LDS (tanh applied); r<32 = a-side, r>=32 = b-side
        #pragma unroll
        for (int mi = 0; mi < 2; ++mi)
            #pragma unroll
            for (int nj = 0; nj < 2; ++nj) {
                int jl = wn * 32 + nj * 16 + lm;
                float bv = b1[n0 + jl];
                #pragma unroll
                for (int qq = 0; qq < 4; ++qq) {
                    int r = wm * 32 + mi * 16 + g * 4 + qq;
                    ht[r][jl] = fast_tanh(acc[mi][nj][qq] + bv);
                }
            }
        __syncthreads();
        // build M + partials: thread (il = t>>2, pq = t&3) handles 8 pairs of col il
        const int il = t >> 2, pq = t & 3;
        float ci = 0.f;
        #pragma unroll 8
        for (int o = 0; o < OO_; ++o) { float wv = W2[o * HH_ + n0 + il]; ci += wv * wv; }
        const float sgn = s ? -1.f : 1.f;
        float b1p = 0.f, hdp = 0.f;
        bf16x8s v0, v1, v2;
        #pragma unroll
        for (int pp = 0; pp < 8; ++pp) {
            int pl = pq * 8 + pp;
            float ha = ht[pl][il];
            float hb = ht[pl + 32][il];
            float da = 1.f - ha * ha, db = 1.f - hb * hb;
            float s11 = sgn * (da * da * ci);
            float s12 = sgn * (-2.f * da * db * ci);
            float s22 = sgn * (db * db * ci);
            v0[pp] = (short)f2bf(s11);
            v1[pp] = (short)f2bf(s12);
            v2[pp] = (short)f2bf(s22);
            b1p += s11 + s12 + s22;
            float d = ha - hb;
            hdp += sgn * d * d;
        }
        size_t base = (size_t)(n0 + il) * 6144 + s * 1024 + p0 + pq * 8;
        *(bf16x8s*)(&Mt[base]) = v0;
        *(bf16x8s*)(&Mt[base + 2048]) = v1;
        *(bf16x8s*)(&Mt[base + 4096]) = v2;
        b1p += __shfl_xor(b1p, 1); b1p += __shfl_xor(b1p, 2);
        hdp += __shfl_xor(hdp, 1); hdp += __shfl_xor(hdp, 2);
        if (pq == 0) { pb1[ry * HH_ + n0 + il] = b1p; phd[ry * HH_ + n0 + il] = hdp; }
    } else {
        __shared__ int sia[64], sib[64];
        const int b2 = bb - 512;
        const int jblk = b2 >> 5, pblk = b2 & 31;
        const int j = jblk * 64 + (t >> 2), pq = t & 3;
        const int p0 = pblk * 64;
        const int s = p0 >> 10;
        const int* IA = s ? an : ap;
        const int* IB = s ? nI : pI;
        if (t < 64) sia[t] = IA[(p0 & 1023) + t];
        else if (t < 128) sib[t - 64] = IB[(p0 & 1023) + (t - 64)];
        __syncthreads();
        short xv[3][16];
        #pragma unroll
        for (int pp = 0; pp < 16; ++pp) {
            int pl = pq * 16 + pp;
            float xa = x[(size_t)sia[pl] * DD_ + j];
            float xb = x[(size_t)sib[pl] * DD_ + j];
            xv[0][pp] = (short)f2bf(xa * xa);
            xv[1][pp] = (short)f2bf(xa * xb);
            xv[2][pp] = (short)f2bf(xb * xb);
        }
        size_t base = (size_t)j * 6144 + p0 + pq * 16;
        #pragma unroll
        for (int term = 0; term < 3; ++term) {
            bf16x8s v0, v1;
            #pragma unroll
            for (int e = 0; e < 8; ++e) { v0[e] = xv[term][e]; v1[e] = xv[term][e + 8]; }
            *(bf16x8s*)(&Xt[base + (size_t)term * 2048]) = v0;
            *(bf16x8s*)(&Xt[base + (size_t)term * 2048 + 8]) = v1;
        }
    }
}

// ============ L2: part[kb][i][j] = sum_{k chunk 384} Mt[i][k]*Xt[j][k] ====
// grid (4 jblk, 8 iblk, 16 kb); BK=128: 3 k-steps, 6 barriers.
__global__ __launch_bounds__(256) void k_gemm2(
    const short* __restrict__ Mt, const short* __restrict__ Xt,
    float* __restrict__ part) {
    __shared__ short As[64 * 128], Bs[64 * 128];   // 32 KB
    const int t = threadIdx.x;
    const int j0 = blockIdx.x * 64;
    const int i0 = blockIdx.y * 64;
    const int kb = blockIdx.z;
    const int row = t >> 2, q = t & 3;
    const int l = t & 63, w = t >> 6;
    const int wm = w >> 1, wn = w & 1;
    const int lm = l & 15, g = l >> 4;
    const short* srcA = &Mt[(size_t)(i0 + row) * 6144 + kb * 384 + q * 32];
    const short* srcB = &Xt[(size_t)(j0 + row) * 6144 + kb * 384 + q * 32];
    f32x4 acc[2][2] = {};
    for (int ks = 0; ks < 3; ++ks) {
        const int k0 = ks * 128;
        #pragma unroll
        for (int jj = 0; jj < 4; ++jj) {
            const int sl = swz16(row, q * 4 + jj) * 8;
            *(bf16x8s*)(&As[row * 128 + sl]) = *(const bf16x8s*)(srcA + k0 + jj * 8);
            *(bf16x8s*)(&Bs[row * 128 + sl]) = *(const bf16x8s*)(srcB + k0 + jj * 8);
        }
        __syncthreads();
        #pragma unroll
        for (int kk = 0; kk < 4; ++kk) {
            bf16x8s a[2], b[2];
            #pragma unroll
            for (int mi = 0; mi < 2; ++mi) {
                int r = wm * 32 + mi * 16 + lm;
                a[mi] = *(const bf16x8s*)(&As[r * 128 + swz16(r, kk * 4 + g) * 8]);
            }
            #pragma unroll
            for (int nj = 0; nj < 2; ++nj) {
                int r = wn * 32 + nj * 16 + lm;
                b[nj] = *(const bf16x8s*)(&Bs[r * 128 + swz16(r, kk * 4 + g) * 8]);
            }
            #pragma unroll
            for (int mi = 0; mi < 2; ++mi)
                #pragma unroll
                for (int nj = 0; nj < 2; ++nj)
                    acc[mi][nj] = __builtin_amdgcn_mfma_f32_16x16x32_bf16(a[mi], b[nj], acc[mi][nj], 0, 0, 0);
        }
        __syncthreads();
    }
    #pragma unroll
    for (int mi = 0; mi < 2; ++mi)
        #pragma unroll
        for (int nj = 0; nj < 2; ++nj) {
            int j = j0 + wn * 32 + nj * 16 + lm;
            #pragma unroll
            for (int qq = 0; qq < 4; ++qq) {
                int i = i0 + wm * 32 + mi * 16 + g * 4 + qq;
                part[((size_t)kb * HH_ + i) * DD_ + j] = acc[mi][nj][qq];
            }
        }
}

// ============ L3: reductions + broadcast + zeros ============
__global__ void k_tail(const float* __restrict__ part, const float* __restrict__ pb1,
                       const float* __restrict__ phd, float* __restrict__ out) {
    int gid = blockIdx.x * 256 + threadIdx.x;
    const int HD = HH_ * DD_;   // 131072
    if (gid < HD) {
        float sv = 0.f;
        #pragma unroll
        for (int kb = 0; kb < 16; ++kb) sv += part[(size_t)kb * HD + gid];
        out[gid] = sv;
    } else if (gid < HD + HH_) {
        int i = gid - HD;
        float sv = 0.f;
        #pragma unroll
        for (int kb = 0; kb < 64; ++kb) sv += pb1[kb * HH_ + i];
        out[gid] = sv;
    } else if (gid < HD + HH_ + OO_ * HH_) {
        int i = (gid - HD - HH_) & (HH_ - 1);
        float sv = 0.f;
        #pragma unroll
        for (int kb = 0; kb < 64; ++kb) sv += phd[kb * HH_ + i];
        out[gid] = sv;
    } else if (gid < HD + HH_ + OO_ * HH_ + OO_) {
        out[gid] = 0.f;
    }
}

extern "C" void kernel_launch(void* const* d_in, const int* in_sizes, int n_in,
                              void* d_out, int out_size, void* d_ws, size_t ws_size,
                              hipStream_t stream) {
    const float* x  = (const float*)d_in[0];
    const float* W1 = (const float*)d_in[1];
    const float* b1 = (const float*)d_in[2];
    const float* W2 = (const float*)d_in[3];
    // d_in[4] = b2 (unused: b2 Jacobians cancel)
    const int* ap = (const int*)d_in[5];
    const int* pI = (const int*)d_in[6];
    const int* an = (const int*)d_in[7];
    const int* nI = (const int*)d_in[8];
    float* out = (float*)d_out;
    float* ws = (float*)d_ws;

    // workspace (float units)
    float* part = ws;                         // 16*131072 = 2097152
    short* Mt   = (short*)(ws + 2097152);     // 512*6144 shorts = 1572864 floats
    short* Xt   = (short*)(ws + 3670016);     // 256*6144 shorts =  786432 floats
    float* pb1  = ws + 4456448;               // 64*512 = 32768
    float* phd  = ws + 4489216;               // 64*512 = 32768

    k_mega<<<dim3(640), dim3(256), 0, stream>>>(x, W1, b1, W2, ap, pI, an, nI,
                                                Mt, Xt, pb1, phd);
    k_gemm2<<<dim3(4, 8, 16), dim3(256), 0, stream>>>(Mt, Xt, part);
    k_tail<<<dim3(643), dim3(256), 0, stream>>>(part, pb1, phd, out);
}

// Round 18
// 30.428 us; speedup vs baseline: 1.1687x; 1.1687x over previous
//
#include <hip/hip_runtime.h>
#include <hip/hip_bf16.h>
#include <math.h>

#define DD_ 256
#define HH_ 512
#define OO_ 64

typedef __attribute__((ext_vector_type(8))) short bf16x8s;
typedef __attribute__((ext_vector_type(4))) float f32x4;
typedef __attribute__((ext_vector_type(4))) unsigned int u32x4;

__device__ __forceinline__ unsigned short f2bf(float f) {
    unsigned u = __float_as_uint(f);
    u += 0x7FFF + ((u >> 16) & 1);   // round-to-nearest-even
    return (unsigned short)(u >> 16);
}
__device__ __forceinline__ float bf2f(unsigned short h) {
    return __uint_as_float(((unsigned)h) << 16);
}
// pack two floats -> one u32 of 2 bf16 (RNE); compiler emits v_cvt_pk_bf16_f32
__device__ __forceinline__ unsigned pk2(float a, float b) {
    __hip_bfloat162 h = __float22bfloat162_rn(make_float2(a, b));
    return *reinterpret_cast<unsigned*>(&h);
}
// 8 floats -> bf16 hi (packed u32x4), via cvt_pk
__device__ __forceinline__ u32x4 pk8hi(const float4& v0, const float4& v1) {
    u32x4 hi;
    hi[0] = pk2(v0.x, v0.y);
    hi[1] = pk2(v0.z, v0.w);
    hi[2] = pk2(v1.x, v1.y);
    hi[3] = pk2(v1.z, v1.w);
    return hi;
}
// 8 floats -> hi/lo bf16 split (4 u32 each), via cvt_pk
__device__ __forceinline__ void cvt8hl(const float4& v0, const float4& v1,
                                       u32x4& hi, u32x4& lo) {
    float f[8] = {v0.x, v0.y, v0.z, v0.w, v1.x, v1.y, v1.z, v1.w};
    #pragma unroll
    for (int e = 0; e < 4; ++e) {
        float a = f[2 * e], b = f[2 * e + 1];
        unsigned h = pk2(a, b);
        float ra = a - __uint_as_float(h << 16);
        float rb = b - __uint_as_float(h & 0xFFFF0000u);
        hi[e] = h;
        lo[e] = pk2(ra, rb);
    }
}
// 8-slot XOR swizzle within a 128B LDS row: frag reads hit all 32 banks 2-way
__device__ __forceinline__ int swz8(int r, int s) {
    return s ^ (r & 7);
}
// tanh via v_exp_f32; |err| ~1e-6
__device__ __forceinline__ float fast_tanh(float z) {
    float e = __expf(2.f * z);
    return 1.f - __fdividef(2.f, e + 1.f);
}

// ============ L1 mega-kernel: grid 640 ============
// bb < 512: fused gemm1 (BK=64; 2-term split-bf16: A_hi x (B_hi+B_lo)) + tanh
//           + build Mt + b1/hd partials.
// bb >= 512: build Xt[256][6144] bf16 (independent work, same launch).
__global__ __launch_bounds__(256) void k_mega(
    const float* __restrict__ x, const float* __restrict__ W1,
    const float* __restrict__ b1, const float* __restrict__ W2,
    const int* __restrict__ ap, const int* __restrict__ pI,
    const int* __restrict__ an, const int* __restrict__ nI,
    short* __restrict__ Mt, short* __restrict__ Xt,
    float* __restrict__ pb1, float* __restrict__ phd) {
    const int t = threadIdx.x;
    const int bb = blockIdx.x;
    if (bb < 512) {
        __shared__ short Ah[64 * 64], Bh[64 * 64], Bl[64 * 64];   // 24 KB
        __shared__ float ht[64][67];   // pad 67: pair-read conflict-free
        __shared__ int sidx[64];
        const int n0 = (bb & 7) * 64;
        const int ry = bb >> 3;
        const int s = ry >> 5;
        const int p0 = (ry & 31) * 32;
        const int* IA = s ? an : ap;
        const int* IB = s ? nI : pI;
        if (t < 32) sidx[t] = IA[p0 + t];
        else if (t < 64) sidx[t] = IB[p0 + t - 32];
        __syncthreads();
        const int row = t >> 2, q = t & 3;          // staging: row 0..63, 16-float slice
        const int l = t & 63, w = t >> 6;
        const int wm = w >> 1, wn = w & 1;          // wave 2x2 over 64x64 tile
        const int lm = l & 15, g = l >> 4;          // frag: m/n = lm, k-slot = g
        const int sl0 = swz8(row, 2 * q) * 8;
        const int sl1 = swz8(row, 2 * q + 1) * 8;
        const float* srcA = x + (size_t)sidx[row] * DD_ + q * 16;
        const float* srcB = W1 + (size_t)(n0 + row) * DD_ + q * 16;
        f32x4 acc[2][2] = {};
        for (int ks = 0; ks < 4; ++ks) {            // BK=64: 4 k-steps
            const int k0 = ks * 64;
            {   // stage A: gathered x rows, fp32 -> bf16 hi only (cvt_pk)
                float4 a0 = *(const float4*)(srcA + k0);
                float4 a1 = *(const float4*)(srcA + k0 + 4);
                float4 a2 = *(const float4*)(srcA + k0 + 8);
                float4 a3 = *(const float4*)(srcA + k0 + 12);
                *(u32x4*)(&Ah[row * 64 + sl0]) = pk8hi(a0, a1);
                *(u32x4*)(&Ah[row * 64 + sl1]) = pk8hi(a2, a3);
            }
            {   // stage B: W1 rows, hi/lo split (cvt_pk)
                float4 b0 = *(const float4*)(srcB + k0);
                float4 b1q = *(const float4*)(srcB + k0 + 4);
                float4 b2 = *(const float4*)(srcB + k0 + 8);
                float4 b3 = *(const float4*)(srcB + k0 + 12);
                u32x4 hi, lo;
                cvt8hl(b0, b1q, hi, lo);
                *(u32x4*)(&Bh[row * 64 + sl0]) = hi;
                *(u32x4*)(&Bl[row * 64 + sl0]) = lo;
                cvt8hl(b2, b3, hi, lo);
                *(u32x4*)(&Bh[row * 64 + sl1]) = hi;
                *(u32x4*)(&Bl[row * 64 + sl1]) = lo;
            }
            __syncthreads();
            #pragma unroll
            for (int kk = 0; kk < 2; ++kk) {        // two K=32 MFMA sub-steps
                bf16x8s ah[2], bh[2], bl[2];
                #pragma unroll
                for (int mi = 0; mi < 2; ++mi) {
                    int r = wm * 32 + mi * 16 + lm;
                    ah[mi] = *(const bf16x8s*)(&Ah[r * 64 + swz8(r, kk * 4 + g) * 8]);
                }
                #pragma unroll
                for (int nj = 0; nj < 2; ++nj) {
                    int r = wn * 32 + nj * 16 + lm;
                    int off = r * 64 + swz8(r, kk * 4 + g) * 8;
                    bh[nj] = *(const bf16x8s*)(&Bh[off]);
                    bl[nj] = *(const bf16x8s*)(&Bl[off]);
                }
                #pragma unroll
                for (int mi = 0; mi < 2; ++mi)
                    #pragma unroll
                    for (int nj = 0; nj < 2; ++nj) {
                        acc[mi][nj] = __builtin_amdgcn_mfma_f32_16x16x32_bf16(ah[mi], bh[nj], acc[mi][nj], 0, 0, 0);
                        acc[mi][nj] = __builtin_amdgcn_mfma_f32_16x16x32_bf16(ah[mi], bl[nj], acc[mi][nj], 0, 0, 0);
                    }
            }
            __syncthreads();
        }
        // h-tile -> LDS (tanh applied); r<32 = a-side, r>=32 = b-side
        #pragma unroll
        for (int mi = 0; mi < 2; ++mi)
            #pragma unroll
            for (int nj = 0; nj < 2; ++nj) {
                int jl = wn * 32 + nj * 16 + lm;
                float bv = b1[n0 + jl];
                #pragma unroll
                for (int qq = 0; qq < 4; ++qq) {
                    int r = wm * 32 + mi * 16 + g * 4 + qq;
                    ht[r][jl] = fast_tanh(acc[mi][nj][qq] + bv);
                }
            }
        __syncthreads();
        // build M + partials: thread (il = t>>2, pq = t&3) handles 8 pairs of col il
        const int il = t >> 2, pq = t & 3;
        float ci = 0.f;
        #pragma unroll 8
        for (int o = 0; o < OO_; ++o) { float wv = W2[o * HH_ + n0 + il]; ci += wv * wv; }
        const float sgn = s ? -1.f : 1.f;
        float b1p = 0.f, hdp = 0.f;
        bf16x8s v0, v1, v2;
        #pragma unroll
        for (int pp = 0; pp < 8; ++pp) {
            int pl = pq * 8 + pp;
            float ha = ht[pl][il];
            float hb = ht[pl + 32][il];
            float da = 1.f - ha * ha, db = 1.f - hb * hb;
            float s11 = sgn * (da * da * ci);
            float s12 = sgn * (-2.f * da * db * ci);
            float s22 = sgn * (db * db * ci);
            v0[pp] = (short)f2bf(s11);
            v1[pp] = (short)f2bf(s12);
            v2[pp] = (short)f2bf(s22);
            b1p += s11 + s12 + s22;
            float d = ha - hb;
            hdp += sgn * d * d;
        }
        size_t base = (size_t)(n0 + il) * 6144 + s * 1024 + p0 + pq * 8;
        *(bf16x8s*)(&Mt[base]) = v0;
        *(bf16x8s*)(&Mt[base + 2048]) = v1;
        *(bf16x8s*)(&Mt[base + 4096]) = v2;
        b1p += __shfl_xor(b1p, 1); b1p += __shfl_xor(b1p, 2);
        hdp += __shfl_xor(hdp, 1); hdp += __shfl_xor(hdp, 2);
        if (pq == 0) { pb1[ry * HH_ + n0 + il] = b1p; phd[ry * HH_ + n0 + il] = hdp; }
    } else {
        __shared__ int sia[64], sib[64];
        const int b2 = bb - 512;
        const int jblk = b2 >> 5, pblk = b2 & 31;
        const int j = jblk * 64 + (t >> 2), pq = t & 3;
        const int p0 = pblk * 64;
        const int s = p0 >> 10;
        const int* IA = s ? an : ap;
        const int* IB = s ? nI : pI;
        if (t < 64) sia[t] = IA[(p0 & 1023) + t];
        else if (t < 128) sib[t - 64] = IB[(p0 & 1023) + (t - 64)];
        __syncthreads();
        short xv[3][16];
        #pragma unroll
        for (int pp = 0; pp < 16; ++pp) {
            int pl = pq * 16 + pp;
            float xa = x[(size_t)sia[pl] * DD_ + j];
            float xb = x[(size_t)sib[pl] * DD_ + j];
            xv[0][pp] = (short)f2bf(xa * xa);
            xv[1][pp] = (short)f2bf(xa * xb);
            xv[2][pp] = (short)f2bf(xb * xb);
        }
        size_t base = (size_t)j * 6144 + p0 + pq * 16;
        #pragma unroll
        for (int term = 0; term < 3; ++term) {
            bf16x8s v0, v1;
            #pragma unroll
            for (int e = 0; e < 8; ++e) { v0[e] = xv[term][e]; v1[e] = xv[term][e + 8]; }
            *(bf16x8s*)(&Xt[base + (size_t)term * 2048]) = v0;
            *(bf16x8s*)(&Xt[base + (size_t)term * 2048 + 8]) = v1;
        }
    }
}

// ============ L2: part[kb][i][j] = sum_{k chunk 384} Mt[i][k]*Xt[j][k] ====
// grid (4 jblk, 8 iblk, 16 kb); BK=64: 6 k-steps, 12 barriers.
__global__ __launch_bounds__(256) void k_gemm2(
    const short* __restrict__ Mt, const short* __restrict__ Xt,
    float* __restrict__ part) {
    __shared__ short As[64 * 64], Bs[64 * 64];   // 16 KB
    const int t = threadIdx.x;
    const int j0 = blockIdx.x * 64;
    const int i0 = blockIdx.y * 64;
    const int kb = blockIdx.z;
    const int row = t >> 2, q = t & 3;
    const int l = t & 63, w = t >> 6;
    const int wm = w >> 1, wn = w & 1;
    const int lm = l & 15, g = l >> 4;
    const int sl0 = swz8(row, 2 * q) * 8;
    const int sl1 = swz8(row, 2 * q + 1) * 8;
    const short* srcA = &Mt[(size_t)(i0 + row) * 6144 + kb * 384 + q * 16];
    const short* srcB = &Xt[(size_t)(j0 + row) * 6144 + kb * 384 + q * 16];
    f32x4 acc[2][2] = {};
    for (int ks = 0; ks < 6; ++ks) {
        const int k0 = ks * 64;
        *(bf16x8s*)(&As[row * 64 + sl0]) = *(const bf16x8s*)(srcA + k0);
        *(bf16x8s*)(&As[row * 64 + sl1]) = *(const bf16x8s*)(srcA + k0 + 8);
        *(bf16x8s*)(&Bs[row * 64 + sl0]) = *(const bf16x8s*)(srcB + k0);
        *(bf16x8s*)(&Bs[row * 64 + sl1]) = *(const bf16x8s*)(srcB + k0 + 8);
        __syncthreads();
        #pragma unroll
        for (int kk = 0; kk < 2; ++kk) {
            bf16x8s a[2], b[2];
            #pragma unroll
            for (int mi = 0; mi < 2; ++mi) {
                int r = wm * 32 + mi * 16 + lm;
                a[mi] = *(const bf16x8s*)(&As[r * 64 + swz8(r, kk * 4 + g) * 8]);
            }
            #pragma unroll
            for (int nj = 0; nj < 2; ++nj) {
                int r = wn * 32 + nj * 16 + lm;
                b[nj] = *(const bf16x8s*)(&Bs[r * 64 + swz8(r, kk * 4 + g) * 8]);
            }
            #pragma unroll
            for (int mi = 0; mi < 2; ++mi)
                #pragma unroll
                for (int nj = 0; nj < 2; ++nj)
                    acc[mi][nj] = __builtin_amdgcn_mfma_f32_16x16x32_bf16(a[mi], b[nj], acc[mi][nj], 0, 0, 0);
        }
        __syncthreads();
    }
    #pragma unroll
    for (int mi = 0; mi < 2; ++mi)
        #pragma unroll
        for (int nj = 0; nj < 2; ++nj) {
            int j = j0 + wn * 32 + nj * 16 + lm;
            #pragma unroll
            for (int qq = 0; qq < 4; ++qq) {
                int i = i0 + wm * 32 + mi * 16 + g * 4 + qq;
                part[((size_t)kb * HH_ + i) * DD_ + j] = acc[mi][nj][qq];
            }
        }
}

// ============ L3: reductions + broadcast + zeros ============
__global__ void k_tail(const float* __restrict__ part, const float* __restrict__ pb1,
                       const float* __restrict__ phd, float* __restrict__ out) {
    int gid = blockIdx.x * 256 + threadIdx.x;
    const int HD = HH_ * DD_;   // 131072
    if (gid < HD) {
        float sv = 0.f;
        #pragma unroll
        for (int kb = 0; kb < 16; ++kb) sv += part[(size_t)kb * HD + gid];
        out[gid] = sv;
    } else if (gid < HD + HH_) {
        int i = gid - HD;
        float sv = 0.f;
        #pragma unroll
        for (int kb = 0; kb < 64; ++kb) sv += pb1[kb * HH_ + i];
        out[gid] = sv;
    } else if (gid < HD + HH_ + OO_ * HH_) {
        int i = (gid - HD - HH_) & (HH_ - 1);
        float sv = 0.f;
        #pragma unroll
        for (int kb = 0; kb < 64; ++kb) sv += phd[kb * HH_ + i];
        out[gid] = sv;
    } else if (gid < HD + HH_ + OO_ * HH_ + OO_) {
        out[gid] = 0.f;
    }
}

extern "C" void kernel_launch(void* const* d_in, const int* in_sizes, int n_in,
                              void* d_out, int out_size, void* d_ws, size_t ws_size,
                              hipStream_t stream) {
    const float* x  = (const float*)d_in[0];
    const float* W1 = (const float*)d_in[1];
    const float* b1 = (const float*)d_in[2];
    const float* W2 = (const float*)d_in[3];
    // d_in[4] = b2 (unused: b2 Jacobians cancel)
    const int* ap = (const int*)d_in[5];
    const int* pI = (const int*)d_in[6];
    const int* an = (const int*)d_in[7];
    const int* nI = (const int*)d_in[8];
    float* out = (float*)d_out;
    float* ws = (float*)d_ws;

    // workspace (float units)
    float* part = ws;                         // 16*131072 = 2097152
    short* Mt   = (short*)(ws + 2097152);     // 512*6144 shorts = 1572864 floats
    short* Xt   = (short*)(ws + 3670016);     // 256*6144 shorts =  786432 floats
    float* pb1  = ws + 4456448;               // 64*512 = 32768
    float* phd  = ws + 4489216;               // 64*512 = 32768

    k_mega<<<dim3(640), dim3(256), 0, stream>>>(x, W1, b1, W2, ap, pI, an, nI,
                                                Mt, Xt, pb1, phd);
    k_gemm2<<<dim3(4, 8, 16), dim3(256), 0, stream>>>(Mt, Xt, part);
    k_tail<<<dim3(643), dim3(256), 0, stream>>>(part, pb1, phd, out);
}